// Round 6
// baseline (195.657 us; speedup 1.0000x reference)
//
#include <hip/hip_runtime.h>

// LSTM_52922587021316 — Round 10: R8's PROVEN v2 epilogue in R5's PROVEN
// clean shell. R9 lesson: fully-merged c-update (N/Q with pair-batched
// rcp of ~2^80 products) breaks numerics in the pre-act tail (absmax
// 7.8e-3 > 3.6e-3). The cell recurrence is the sensitive path — keep its
// division per-element. R8's v2 epilogue (trans 7.5/h) passed at baseline
// absmax 9.77e-4; its only problem was the 512-thread shell spilling
// (WRITE 24.8MB, VALUBusy 73.7). R5's 256-thread (256,2) shell is the
// only spill-free one measured (VGPR budget 256, WRITE exactly 1MB).
// This round composes the two. Predicted: WRITE ~1MB, dur ~120-128us.
//   i*g       = (Ed-1)*rcp((1+Ea)(1+Ed))     [bounded <= ~2^50]
//   o*tanh(c) = (Ec-1)*rcp((1+Ee)(1+Ec))     [bounded <= ~2^50]
//   f pair    = rcp batched across r-pairs    [Db0*Db1 <= ~2^34]

#define HID 32
#define TSTEPS 7
#define LSTRIDE 40   // halves per LDS h-row: 32 + 8 pad (80 B, 16B-aligned)
#define NWAVES 4     // waves per block

typedef _Float16 half8 __attribute__((ext_vector_type(8)));
typedef float floatx4 __attribute__((ext_vector_type(4)));
typedef float floatx2 __attribute__((ext_vector_type(2)));

#define LOG2E 1.44269504088896f

__device__ __forceinline__ float fast_rcp(float x) { return __builtin_amdgcn_rcpf(x); }

__device__ __forceinline__ float exp2_fast(float x) {
#if __has_builtin(__builtin_amdgcn_exp2f)
    return __builtin_amdgcn_exp2f(x);
#else
    return __expf(x * 0.69314718055994531f);
#endif
}

__global__ __launch_bounds__(256, 2) void lstm2_mfma(
    const float* __restrict__ xin,   // [B, 7]
    const float* __restrict__ Wih0,  // [128, 1]
    const float* __restrict__ Whh0,  // [128, 32]
    const float* __restrict__ bih0,  // [128]
    const float* __restrict__ bhh0,  // [128]
    const float* __restrict__ Wih1,  // [128, 32]
    const float* __restrict__ Whh1,  // [128, 32]
    const float* __restrict__ bih1,  // [128]
    const float* __restrict__ bhh1,  // [128]
    const float* __restrict__ fcw,   // [32]
    const float* __restrict__ fcb,   // [1]
    const float* __restrict__ fc1w,  // [7]
    const float* __restrict__ fc1b,  // [1]
    float* __restrict__ out,         // [B]
    int B)
{
    const int lane = threadIdx.x & 63;
    const int wave = threadIdx.x >> 6;
    const int col  = lane & 15;          // C col / A row m
    const int rg   = lane >> 4;          // C rows rg*4..+3 / A k-chunk rg*8..+7
    const int seq_base = (blockIdx.x * NWAVES + wave) * 16;

    // Weight fragments, block-shared, per-lane order:
    // matrix m in {0:Whh0, 1:Wih1, 2:Whh1}, tile nt (0..7), lane, 8 halves.
    // byte offset = m*8192 + nt*1024 + lane*16  -> ds_read_b128, conflict-free.
    __shared__ __align__(16) _Float16 ldsw[3 * 8 * 64 * 8];   // 24 KiB
    __shared__ __align__(16) floatx2  ldsbw0[128];            // {b0s, wx} by n, 1 KiB
    __shared__ float                  ldsb1[128];             // b1s by n, 0.5 KiB
    __shared__ __align__(16) _Float16 ldsh[NWAVES][2][16 * LSTRIDE];
    __shared__ __align__(16) float    ldsx[NWAVES][TSTEPS * 16];

    _Float16* h1l = &ldsh[wave][0][0];
    _Float16* h2l = &ldsh[wave][1][0];
    float* xl = &ldsx[wave][0];

    // ---- stage x: 112 contiguous floats per wave -> transposed [t][seq] ---
#pragma unroll
    for (int e = lane; e < TSTEPS * 16; e += 64) {
        const int s = e / TSTEPS;
        const int tt = e - s * TSTEPS;
        xl[tt * 16 + s] = xin[seq_base * TSTEPS + e];
    }

    // ---- stage prescaled weights/biases into LDS (once per block) --------
    if (wave < 3) {
        const float* Wsrc = (wave == 0) ? Whh0 : (wave == 1) ? Wih1 : Whh1;
#pragma unroll
        for (int nt = 0; nt < 8; ++nt) {
            const int n = nt * 16 + col;
            const float sc = ((n >> 5) == 2) ? (2.0f * LOG2E) : (-LOG2E);
            const float* s = Wsrc + n * HID + rg * 8;
            half8 f;
#pragma unroll
            for (int j = 0; j < 8; ++j) f[j] = (_Float16)(sc * s[j]);
            *(half8*)&ldsw[((wave * 8 + nt) * 64 + lane) * 8] = f;
        }
    } else {
#pragma unroll
        for (int i = 0; i < 2; ++i) {
            const int n = i * 64 + lane;
            const float sc = ((n >> 5) == 2) ? (2.0f * LOG2E) : (-LOG2E);
            floatx2 bw;
            bw[0] = sc * (bih0[n] + bhh0[n]);   // prescaled layer-0 bias
            bw[1] = sc * Wih0[n];               // prescaled rank-1 x weight
            ldsbw0[n] = bw;
            ldsb1[n]  = sc * (bih1[n] + bhh1[n]);
        }
    }
    __syncthreads();

    const float fcw_l0 = fcw[col];
    const float fcw_l1 = fcw[16 + col];

    half8 Ah1 = {};      // h1 in A-layout (zero at t=0)
    half8 Ah2 = {};      // h2 in A-layout
    float c1[2][4] = {}, c2[2][4] = {};
    float facc[4] = {0.f, 0.f, 0.f, 0.f};

    for (int t = 0; t < TSTEPS; ++t) {
        // Opaque zero offset: makes the LDS weight addresses loop-variant so
        // LICM cannot hoist the 24 fragment loads back into 96 registers.
        unsigned woff = 0;
        asm volatile("" : "+v"(woff));
        const char* wB  = (const char*)ldsw   + lane * 16 + woff;
        const char* bB0 = (const char*)ldsbw0 + col * 8  + woff;
        const char* bB1 = (const char*)ldsb1  + col * 4  + woff;

        // x for my 4 C-rows (m = rg*4 + r): one b128, conflict-free broadcast
        const floatx4 xr = *(const floatx4*)&xl[t * 16 + rg * 4];

        // -------- layer 0: gates = (bias + x*Wih0) + h1_prev @ Whh0^T -----
        floatx4 g0[8];
#pragma unroll
        for (int nt = 0; nt < 8; ++nt) {
            const floatx2 bw = *(const floatx2*)(bB0 + nt * 128);
            const half8 bf   = *(const half8*)(wB + nt * 1024);
            floatx4 c;
#pragma unroll
            for (int r = 0; r < 4; ++r) c[r] = fmaf(bw[1], xr[r], bw[0]);
            g0[nt] = __builtin_amdgcn_mfma_f32_16x16x32_f16(Ah1, bf, c, 0, 0, 0);
        }

        // epilogue 0: v2 cell update (merged-rcp, per-element c path),
        // write h1_new to LDS
#pragma unroll
        for (int q = 0; q < 2; ++q) {
#pragma unroll
            for (int rp = 0; rp < 2; ++rp) {
                float Ea[2], Db[2], Ed[2], Ee[2];
#pragma unroll
                for (int e = 0; e < 2; ++e) {
                    const int r = rp * 2 + e;
                    Ea[e] = exp2_fast(g0[0 + q][r]);
                    Db[e] = 1.0f + exp2_fast(g0[2 + q][r]);
                    Ed[e] = exp2_fast(g0[4 + q][r]);
                    Ee[e] = exp2_fast(g0[6 + q][r]);
                }
                const float Rb = fast_rcp(Db[0] * Db[1]);
#pragma unroll
                for (int e = 0; e < 2; ++e) {
                    const int r = rp * 2 + e;
                    const float ff  = Rb * Db[1 - e];
                    const float Rig = fast_rcp((1.0f + Ea[e]) * (1.0f + Ed[e]));
                    const float ig  = fmaf(Ed[e], Rig, -Rig);
                    const float c   = fmaf(ff, c1[q][r], ig);
                    c1[q][r] = c;
                    const float Ec  = exp2_fast(c * (2.0f * LOG2E));
                    const float Rh  = fast_rcp((1.0f + Ee[e]) * (1.0f + Ec));
                    const float h   = fmaf(Ec, Rh, -Rh);
                    h1l[(rg * 4 + r) * LSTRIDE + q * 16 + col] = (_Float16)h;
                }
            }
        }
        Ah1 = *(const half8*)&h1l[col * LSTRIDE + rg * 8];

        // -------- layer 1: gates = bias + h1_new @ Wih1^T + h2_prev @ Whh1^T
        floatx4 g1[8];
#pragma unroll
        for (int nt = 0; nt < 8; ++nt) {
            const float b1  = *(const float*)(bB1 + nt * 64);
            const half8 f1a = *(const half8*)(wB + 8192  + nt * 1024);
            const half8 f1b = *(const half8*)(wB + 16384 + nt * 1024);
            floatx4 c = {b1, b1, b1, b1};
            c = __builtin_amdgcn_mfma_f32_16x16x32_f16(Ah1, f1a, c, 0, 0, 0);
            g1[nt] = __builtin_amdgcn_mfma_f32_16x16x32_f16(Ah2, f1b, c, 0, 0, 0);
        }

        // epilogue 1: v2 cell update, fc partial, write h2_new to LDS
        const float f1t = fc1w[t];
        const float w0 = f1t * fcw_l0;
        const float w1 = f1t * fcw_l1;
#pragma unroll
        for (int q = 0; q < 2; ++q) {
            const float wq = q ? w1 : w0;
#pragma unroll
            for (int rp = 0; rp < 2; ++rp) {
                float Ea[2], Db[2], Ed[2], Ee[2];
#pragma unroll
                for (int e = 0; e < 2; ++e) {
                    const int r = rp * 2 + e;
                    Ea[e] = exp2_fast(g1[0 + q][r]);
                    Db[e] = 1.0f + exp2_fast(g1[2 + q][r]);
                    Ed[e] = exp2_fast(g1[4 + q][r]);
                    Ee[e] = exp2_fast(g1[6 + q][r]);
                }
                const float Rb = fast_rcp(Db[0] * Db[1]);
#pragma unroll
                for (int e = 0; e < 2; ++e) {
                    const int r = rp * 2 + e;
                    const float ff  = Rb * Db[1 - e];
                    const float Rig = fast_rcp((1.0f + Ea[e]) * (1.0f + Ed[e]));
                    const float ig  = fmaf(Ed[e], Rig, -Rig);
                    const float c   = fmaf(ff, c2[q][r], ig);
                    c2[q][r] = c;
                    const float Ec  = exp2_fast(c * (2.0f * LOG2E));
                    const float Rh  = fast_rcp((1.0f + Ee[e]) * (1.0f + Ec));
                    const float h   = fmaf(Ec, Rh, -Rh);
                    facc[r] = fmaf(wq, h, facc[r]);
                    h2l[(rg * 4 + r) * LSTRIDE + q * 16 + col] = (_Float16)h;
                }
            }
        }
        Ah2 = *(const half8*)&h2l[col * LSTRIDE + rg * 8];
    }

    // ---- reduce fc partials across the 16 cols, add constant tail --------
#pragma unroll
    for (int r = 0; r < 4; ++r) {
        float v = facc[r];
        v += __shfl_xor(v, 1);
        v += __shfl_xor(v, 2);
        v += __shfl_xor(v, 4);
        v += __shfl_xor(v, 8);
        facc[r] = v;
    }
    float sum_f1 = 0.f;
#pragma unroll
    for (int t = 0; t < TSTEPS; ++t) sum_f1 += fc1w[t];
    const float tail = fcb[0] * sum_f1 + fc1b[0];

    if (col == 0) {
#pragma unroll
        for (int r = 0; r < 4; ++r)
            out[seq_base + rg * 4 + r] = facc[r] + tail;
    }
}

extern "C" void kernel_launch(void* const* d_in, const int* in_sizes, int n_in,
                              void* d_out, int out_size, void* d_ws, size_t ws_size,
                              hipStream_t stream) {
    const float* xin  = (const float*)d_in[0];
    const float* Wih0 = (const float*)d_in[1];
    const float* Whh0 = (const float*)d_in[2];
    const float* bih0 = (const float*)d_in[3];
    const float* bhh0 = (const float*)d_in[4];
    const float* Wih1 = (const float*)d_in[5];
    const float* Whh1 = (const float*)d_in[6];
    const float* bih1 = (const float*)d_in[7];
    const float* bhh1 = (const float*)d_in[8];
    const float* fcw  = (const float*)d_in[9];
    const float* fcb  = (const float*)d_in[10];
    const float* fc1w = (const float*)d_in[11];
    const float* fc1b = (const float*)d_in[12];
    float* out = (float*)d_out;

    const int B = in_sizes[0] / TSTEPS;       // [B, T, F=1]
    const int grid = B / (NWAVES * 16);       // 1 block = 4 waves = 64 sequences
    lstm2_mfma<<<grid, NWAVES * 64, 0, stream>>>(
        xin, Wih0, Whh0, bih0, bhh0, Wih1, Whh1, bih1, bhh1,
        fcw, fcb, fc1w, fc1b, out, B);
}

// Round 7
// 194.131 us; speedup vs baseline: 1.0079x; 1.0079x over previous
//
#include <hip/hip_runtime.h>

// LSTM_52922587021316 — Round 10: R8's PROVEN v2 epilogue in R5's PROVEN
// clean shell. R9 lesson: fully-merged c-update (N/Q with pair-batched
// rcp of ~2^80 products) breaks numerics in the pre-act tail (absmax
// 7.8e-3 > 3.6e-3). The cell recurrence is the sensitive path — keep its
// division per-element. R8's v2 epilogue (trans 7.5/h) passed at baseline
// absmax 9.77e-4; its only problem was the 512-thread shell spilling
// (WRITE 24.8MB, VALUBusy 73.7). R5's 256-thread (256,2) shell is the
// only spill-free one measured (VGPR budget 256, WRITE exactly 1MB).
// This round composes the two. Predicted: WRITE ~1MB, dur ~120-128us.
//   i*g       = (Ed-1)*rcp((1+Ea)(1+Ed))     [bounded <= ~2^50]
//   o*tanh(c) = (Ec-1)*rcp((1+Ee)(1+Ec))     [bounded <= ~2^50]
//   f pair    = rcp batched across r-pairs    [Db0*Db1 <= ~2^34]

#define HID 32
#define TSTEPS 7
#define LSTRIDE 40   // halves per LDS h-row: 32 + 8 pad (80 B, 16B-aligned)
#define NWAVES 4     // waves per block

typedef _Float16 half8 __attribute__((ext_vector_type(8)));
typedef float floatx4 __attribute__((ext_vector_type(4)));
typedef float floatx2 __attribute__((ext_vector_type(2)));

#define LOG2E 1.44269504088896f

__device__ __forceinline__ float fast_rcp(float x) { return __builtin_amdgcn_rcpf(x); }

__device__ __forceinline__ float exp2_fast(float x) {
#if __has_builtin(__builtin_amdgcn_exp2f)
    return __builtin_amdgcn_exp2f(x);
#else
    return __expf(x * 0.69314718055994531f);
#endif
}

__global__ __launch_bounds__(256, 2) void lstm2_mfma(
    const float* __restrict__ xin,   // [B, 7]
    const float* __restrict__ Wih0,  // [128, 1]
    const float* __restrict__ Whh0,  // [128, 32]
    const float* __restrict__ bih0,  // [128]
    const float* __restrict__ bhh0,  // [128]
    const float* __restrict__ Wih1,  // [128, 32]
    const float* __restrict__ Whh1,  // [128, 32]
    const float* __restrict__ bih1,  // [128]
    const float* __restrict__ bhh1,  // [128]
    const float* __restrict__ fcw,   // [32]
    const float* __restrict__ fcb,   // [1]
    const float* __restrict__ fc1w,  // [7]
    const float* __restrict__ fc1b,  // [1]
    float* __restrict__ out,         // [B]
    int B)
{
    const int lane = threadIdx.x & 63;
    const int wave = threadIdx.x >> 6;
    const int col  = lane & 15;          // C col / A row m
    const int rg   = lane >> 4;          // C rows rg*4..+3 / A k-chunk rg*8..+7
    const int seq_base = (blockIdx.x * NWAVES + wave) * 16;

    // Weight fragments, block-shared, per-lane order:
    // matrix m in {0:Whh0, 1:Wih1, 2:Whh1}, tile nt (0..7), lane, 8 halves.
    // byte offset = m*8192 + nt*1024 + lane*16  -> ds_read_b128, conflict-free.
    __shared__ __align__(16) _Float16 ldsw[3 * 8 * 64 * 8];   // 24 KiB
    __shared__ __align__(16) floatx2  ldsbw0[128];            // {b0s, wx} by n, 1 KiB
    __shared__ float                  ldsb1[128];             // b1s by n, 0.5 KiB
    __shared__ __align__(16) _Float16 ldsh[NWAVES][2][16 * LSTRIDE];
    __shared__ __align__(16) float    ldsx[NWAVES][TSTEPS * 16];

    _Float16* h1l = &ldsh[wave][0][0];
    _Float16* h2l = &ldsh[wave][1][0];
    float* xl = &ldsx[wave][0];

    // ---- stage x: 112 contiguous floats per wave -> transposed [t][seq] ---
#pragma unroll
    for (int e = lane; e < TSTEPS * 16; e += 64) {
        const int s = e / TSTEPS;
        const int tt = e - s * TSTEPS;
        xl[tt * 16 + s] = xin[seq_base * TSTEPS + e];
    }

    // ---- stage prescaled weights/biases into LDS (once per block) --------
    if (wave < 3) {
        const float* Wsrc = (wave == 0) ? Whh0 : (wave == 1) ? Wih1 : Whh1;
#pragma unroll
        for (int nt = 0; nt < 8; ++nt) {
            const int n = nt * 16 + col;
            const float sc = ((n >> 5) == 2) ? (2.0f * LOG2E) : (-LOG2E);
            const float* s = Wsrc + n * HID + rg * 8;
            half8 f;
#pragma unroll
            for (int j = 0; j < 8; ++j) f[j] = (_Float16)(sc * s[j]);
            *(half8*)&ldsw[((wave * 8 + nt) * 64 + lane) * 8] = f;
        }
    } else {
#pragma unroll
        for (int i = 0; i < 2; ++i) {
            const int n = i * 64 + lane;
            const float sc = ((n >> 5) == 2) ? (2.0f * LOG2E) : (-LOG2E);
            floatx2 bw;
            bw[0] = sc * (bih0[n] + bhh0[n]);   // prescaled layer-0 bias
            bw[1] = sc * Wih0[n];               // prescaled rank-1 x weight
            ldsbw0[n] = bw;
            ldsb1[n]  = sc * (bih1[n] + bhh1[n]);
        }
    }
    __syncthreads();

    const float fcw_l0 = fcw[col];
    const float fcw_l1 = fcw[16 + col];

    half8 Ah1 = {};      // h1 in A-layout (zero at t=0)
    half8 Ah2 = {};      // h2 in A-layout
    float c1[2][4] = {}, c2[2][4] = {};
    float facc[4] = {0.f, 0.f, 0.f, 0.f};

    for (int t = 0; t < TSTEPS; ++t) {
        // Opaque zero offset: makes the LDS weight addresses loop-variant so
        // LICM cannot hoist the 24 fragment loads back into 96 registers.
        unsigned woff = 0;
        asm volatile("" : "+v"(woff));
        const char* wB  = (const char*)ldsw   + lane * 16 + woff;
        const char* bB0 = (const char*)ldsbw0 + col * 8  + woff;
        const char* bB1 = (const char*)ldsb1  + col * 4  + woff;

        // x for my 4 C-rows (m = rg*4 + r): one b128, conflict-free broadcast
        const floatx4 xr = *(const floatx4*)&xl[t * 16 + rg * 4];

        // -------- layer 0: gates = (bias + x*Wih0) + h1_prev @ Whh0^T -----
        floatx4 g0[8];
#pragma unroll
        for (int nt = 0; nt < 8; ++nt) {
            const floatx2 bw = *(const floatx2*)(bB0 + nt * 128);
            const half8 bf   = *(const half8*)(wB + nt * 1024);
            floatx4 c;
#pragma unroll
            for (int r = 0; r < 4; ++r) c[r] = fmaf(bw[1], xr[r], bw[0]);
            g0[nt] = __builtin_amdgcn_mfma_f32_16x16x32_f16(Ah1, bf, c, 0, 0, 0);
        }

        // epilogue 0: v2 cell update (merged-rcp, per-element c path),
        // write h1_new to LDS
#pragma unroll
        for (int q = 0; q < 2; ++q) {
#pragma unroll
            for (int rp = 0; rp < 2; ++rp) {
                float Ea[2], Db[2], Ed[2], Ee[2];
#pragma unroll
                for (int e = 0; e < 2; ++e) {
                    const int r = rp * 2 + e;
                    Ea[e] = exp2_fast(g0[0 + q][r]);
                    Db[e] = 1.0f + exp2_fast(g0[2 + q][r]);
                    Ed[e] = exp2_fast(g0[4 + q][r]);
                    Ee[e] = exp2_fast(g0[6 + q][r]);
                }
                const float Rb = fast_rcp(Db[0] * Db[1]);
#pragma unroll
                for (int e = 0; e < 2; ++e) {
                    const int r = rp * 2 + e;
                    const float ff  = Rb * Db[1 - e];
                    const float Rig = fast_rcp((1.0f + Ea[e]) * (1.0f + Ed[e]));
                    const float ig  = fmaf(Ed[e], Rig, -Rig);
                    const float c   = fmaf(ff, c1[q][r], ig);
                    c1[q][r] = c;
                    const float Ec  = exp2_fast(c * (2.0f * LOG2E));
                    const float Rh  = fast_rcp((1.0f + Ee[e]) * (1.0f + Ec));
                    const float h   = fmaf(Ec, Rh, -Rh);
                    h1l[(rg * 4 + r) * LSTRIDE + q * 16 + col] = (_Float16)h;
                }
            }
        }
        Ah1 = *(const half8*)&h1l[col * LSTRIDE + rg * 8];

        // -------- layer 1: gates = bias + h1_new @ Wih1^T + h2_prev @ Whh1^T
        floatx4 g1[8];
#pragma unroll
        for (int nt = 0; nt < 8; ++nt) {
            const float b1  = *(const float*)(bB1 + nt * 64);
            const half8 f1a = *(const half8*)(wB + 8192  + nt * 1024);
            const half8 f1b = *(const half8*)(wB + 16384 + nt * 1024);
            floatx4 c = {b1, b1, b1, b1};
            c = __builtin_amdgcn_mfma_f32_16x16x32_f16(Ah1, f1a, c, 0, 0, 0);
            g1[nt] = __builtin_amdgcn_mfma_f32_16x16x32_f16(Ah2, f1b, c, 0, 0, 0);
        }

        // epilogue 1: v2 cell update, fc partial, write h2_new to LDS
        const float f1t = fc1w[t];
        const float w0 = f1t * fcw_l0;
        const float w1 = f1t * fcw_l1;
#pragma unroll
        for (int q = 0; q < 2; ++q) {
            const float wq = q ? w1 : w0;
#pragma unroll
            for (int rp = 0; rp < 2; ++rp) {
                float Ea[2], Db[2], Ed[2], Ee[2];
#pragma unroll
                for (int e = 0; e < 2; ++e) {
                    const int r = rp * 2 + e;
                    Ea[e] = exp2_fast(g1[0 + q][r]);
                    Db[e] = 1.0f + exp2_fast(g1[2 + q][r]);
                    Ed[e] = exp2_fast(g1[4 + q][r]);
                    Ee[e] = exp2_fast(g1[6 + q][r]);
                }
                const float Rb = fast_rcp(Db[0] * Db[1]);
#pragma unroll
                for (int e = 0; e < 2; ++e) {
                    const int r = rp * 2 + e;
                    const float ff  = Rb * Db[1 - e];
                    const float Rig = fast_rcp((1.0f + Ea[e]) * (1.0f + Ed[e]));
                    const float ig  = fmaf(Ed[e], Rig, -Rig);
                    const float c   = fmaf(ff, c2[q][r], ig);
                    c2[q][r] = c;
                    const float Ec  = exp2_fast(c * (2.0f * LOG2E));
                    const float Rh  = fast_rcp((1.0f + Ee[e]) * (1.0f + Ec));
                    const float h   = fmaf(Ec, Rh, -Rh);
                    facc[r] = fmaf(wq, h, facc[r]);
                    h2l[(rg * 4 + r) * LSTRIDE + q * 16 + col] = (_Float16)h;
                }
            }
        }
        Ah2 = *(const half8*)&h2l[col * LSTRIDE + rg * 8];
    }

    // ---- reduce fc partials across the 16 cols, add constant tail --------
#pragma unroll
    for (int r = 0; r < 4; ++r) {
        float v = facc[r];
        v += __shfl_xor(v, 1);
        v += __shfl_xor(v, 2);
        v += __shfl_xor(v, 4);
        v += __shfl_xor(v, 8);
        facc[r] = v;
    }
    float sum_f1 = 0.f;
#pragma unroll
    for (int t = 0; t < TSTEPS; ++t) sum_f1 += fc1w[t];
    const float tail = fcb[0] * sum_f1 + fc1b[0];

    if (col == 0) {
#pragma unroll
        for (int r = 0; r < 4; ++r)
            out[seq_base + rg * 4 + r] = facc[r] + tail;
    }
}

extern "C" void kernel_launch(void* const* d_in, const int* in_sizes, int n_in,
                              void* d_out, int out_size, void* d_ws, size_t ws_size,
                              hipStream_t stream) {
    const float* xin  = (const float*)d_in[0];
    const float* Wih0 = (const float*)d_in[1];
    const float* Whh0 = (const float*)d_in[2];
    const float* bih0 = (const float*)d_in[3];
    const float* bhh0 = (const float*)d_in[4];
    const float* Wih1 = (const float*)d_in[5];
    const float* Whh1 = (const float*)d_in[6];
    const float* bih1 = (const float*)d_in[7];
    const float* bhh1 = (const float*)d_in[8];
    const float* fcw  = (const float*)d_in[9];
    const float* fcb  = (const float*)d_in[10];
    const float* fc1w = (const float*)d_in[11];
    const float* fc1b = (const float*)d_in[12];
    float* out = (float*)d_out;

    const int B = in_sizes[0] / TSTEPS;       // [B, T, F=1]
    const int grid = B / (NWAVES * 16);       // 1 block = 4 waves = 64 sequences
    lstm2_mfma<<<grid, NWAVES * 64, 0, stream>>>(
        xin, Wih0, Whh0, bih0, bhh0, Wih1, Whh1, bih1, bhh1,
        fcw, fcb, fc1w, fc1b, out, B);
}